// Round 1
// baseline (483.795 us; speedup 1.0000x reference)
//
#include <hip/hip_runtime.h>
#include <math.h>

// Problem constants (match reference): B=65536, D_IN=1024, D_OUT=1024, 4 qubits, 1 layer.
#define D_IN_K  1024
#define D_OUT_K 1024

static constexpr float PI_F = 3.14159265358979323846f;

// ---------------------------------------------------------------------------
// Kernel 1: h[b][q] = tanh( dot(x[b,:], pre_w[q,:]) + pre_b[q] ) * pi
// One wave (64 lanes) per row; coalesced float4 loads; shuffle reduction.
// ---------------------------------------------------------------------------
__global__ __launch_bounds__(256) void pre_kernel(
    const float* __restrict__ x, const float* __restrict__ pw,
    const float* __restrict__ pb, float* __restrict__ h, int B)
{
    int row  = (blockIdx.x << 2) + (threadIdx.x >> 6);   // 4 rows per block (wave/row)
    int lane = threadIdx.x & 63;
    if (row >= B) return;

    const float4* xr = reinterpret_cast<const float4*>(x + (size_t)row * D_IN_K);
    const float4* w0 = reinterpret_cast<const float4*>(pw);
    const float4* w1 = reinterpret_cast<const float4*>(pw + D_IN_K);
    const float4* w2 = reinterpret_cast<const float4*>(pw + 2 * D_IN_K);
    const float4* w3 = reinterpret_cast<const float4*>(pw + 3 * D_IN_K);

    float p0 = 0.f, p1 = 0.f, p2 = 0.f, p3 = 0.f;
#pragma unroll
    for (int k = 0; k < 4; ++k) {
        int idx = lane + (k << 6);             // float4 index 0..255
        float4 xv = xr[idx];
        float4 a = w0[idx], b = w1[idx], c = w2[idx], d = w3[idx];
        p0 = fmaf(xv.x, a.x, fmaf(xv.y, a.y, fmaf(xv.z, a.z, fmaf(xv.w, a.w, p0))));
        p1 = fmaf(xv.x, b.x, fmaf(xv.y, b.y, fmaf(xv.z, b.z, fmaf(xv.w, b.w, p1))));
        p2 = fmaf(xv.x, c.x, fmaf(xv.y, c.y, fmaf(xv.z, c.z, fmaf(xv.w, c.w, p2))));
        p3 = fmaf(xv.x, d.x, fmaf(xv.y, d.y, fmaf(xv.z, d.z, fmaf(xv.w, d.w, p3))));
    }
#pragma unroll
    for (int off = 32; off > 0; off >>= 1) {
        p0 += __shfl_down(p0, off, 64);
        p1 += __shfl_down(p1, off, 64);
        p2 += __shfl_down(p2, off, 64);
        p3 += __shfl_down(p3, off, 64);
    }
    if (lane == 0) {
        float4 hv;
        hv.x = tanhf(p0 + pb[0]) * PI_F;
        hv.y = tanhf(p1 + pb[1]) * PI_F;
        hv.z = tanhf(p2 + pb[2]) * PI_F;
        hv.w = tanhf(p3 + pb[3]) * PI_F;
        reinterpret_cast<float4*>(h)[row] = hv;
    }
}

// ---------------------------------------------------------------------------
// Kernel 2: 4-qubit statevector simulation, one thread per row, all 16 complex
// amplitudes in registers (fully unrolled, compile-time masks).
// Index convention (matches reference reshape (b,2,2,2,2)): wire w -> bit (3-w).
// ---------------------------------------------------------------------------
template <int MASK>
__device__ __forceinline__ void apply1q(
    float* pr, float* pim,
    float u00r, float u00i, float u01r, float u01i,
    float u10r, float u10i, float u11r, float u11i)
{
#pragma unroll
    for (int j = 0; j < 16; ++j) {
        if (j & MASK) continue;
        const int k = j | MASK;
        float a0r = pr[j], a0i = pim[j], a1r = pr[k], a1i = pim[k];
        pr[j]  = u00r * a0r - u00i * a0i + u01r * a1r - u01i * a1i;
        pim[j] = u00r * a0i + u00i * a0r + u01r * a1i + u01i * a1r;
        pr[k]  = u10r * a0r - u10i * a0i + u11r * a1r - u11i * a1i;
        pim[k] = u10r * a0i + u10i * a0r + u11r * a1i + u11i * a1r;
    }
}

template <int CMASK, int TMASK>
__device__ __forceinline__ void cnot(float* pr, float* pim)
{
#pragma unroll
    for (int j = 0; j < 16; ++j) {
        if ((j & CMASK) && !(j & TMASK)) {
            const int k = j | TMASK;
            float t;
            t = pr[j];  pr[j]  = pr[k];  pr[k]  = t;
            t = pim[j]; pim[j] = pim[k]; pim[k] = t;
        }
    }
}

template <int MASK>
__device__ __forceinline__ void encode_qubit(float* pr, float* pim, float f)
{
    const float r = 0.70710678118654752440f;
    // H
    apply1q<MASK>(pr, pim, r, 0.f, r, 0.f, r, 0.f, -r, 0.f);
    // RY(arctan(f))
    float th = atanf(f) * 0.5f;
    float s, c;
    sincosf(th, &s, &c);
    apply1q<MASK>(pr, pim, c, 0.f, -s, 0.f, s, 0.f, c, 0.f);
    // RZ(arctan(f^2)) = diag(e^{-ia/2}, e^{+ia/2})
    float al = atanf(f * f) * 0.5f;
    float sa, ca;
    sincosf(al, &sa, &ca);
    apply1q<MASK>(pr, pim, ca, -sa, 0.f, 0.f, 0.f, 0.f, ca, sa);
}

template <int MASK>
__device__ __forceinline__ void rot_qubit(float* pr, float* pim,
                                          float phi, float th, float om)
{
    float st, ct, sp, cp, sm, cm;
    sincosf(0.5f * th, &st, &ct);
    sincosf(0.5f * (phi + om), &sp, &cp);
    sincosf(0.5f * (phi - om), &sm, &cm);
    // [[ e^{-i(phi+om)/2} c , -e^{+i(phi-om)/2} s ],
    //  [ e^{-i(phi-om)/2} s ,  e^{+i(phi+om)/2} c ]]
    apply1q<MASK>(pr, pim,
                  ct * cp, -ct * sp,
                  -st * cm, -st * sm,
                  st * cm, -st * sm,
                  ct * cp, ct * sp);
}

__global__ __launch_bounds__(256) void circuit_kernel(
    const float* __restrict__ h, const float* __restrict__ qw,
    float* __restrict__ z, int B)
{
    int b = blockIdx.x * 256 + threadIdx.x;
    if (b >= B) return;

    float4 hv = reinterpret_cast<const float4*>(h)[b];

    float pr[16], pim[16];
#pragma unroll
    for (int j = 0; j < 16; ++j) { pr[j] = 0.f; pim[j] = 0.f; }
    pr[0] = 1.f;

    // Per-qubit encoding: H, RY(atan(f)), RZ(atan(f^2)).  wire i -> mask 8>>i
    encode_qubit<8>(pr, pim, hv.x);
    encode_qubit<4>(pr, pim, hv.y);
    encode_qubit<2>(pr, pim, hv.z);
    encode_qubit<1>(pr, pim, hv.w);

    // CNOT ring: (c=0,t=1), (1,2), (2,3), (3,0)
    cnot<8, 4>(pr, pim);
    cnot<4, 2>(pr, pim);
    cnot<2, 1>(pr, pim);
    cnot<1, 8>(pr, pim);

    // Shared-weight Rot per qubit (layer 0)
    rot_qubit<8>(pr, pim, qw[0], qw[1], qw[2]);
    rot_qubit<4>(pr, pim, qw[3], qw[4], qw[5]);
    rot_qubit<2>(pr, pim, qw[6], qw[7], qw[8]);
    rot_qubit<1>(pr, pim, qw[9], qw[10], qw[11]);

    // z[q] = sum_j |psi_j|^2 * (1 - 2*bit_{3-q}(j))
    float z0 = 0.f, z1 = 0.f, z2 = 0.f, z3 = 0.f;
#pragma unroll
    for (int j = 0; j < 16; ++j) {
        float p = pr[j] * pr[j] + pim[j] * pim[j];
        z0 += (j & 8) ? -p : p;
        z1 += (j & 4) ? -p : p;
        z2 += (j & 2) ? -p : p;
        z3 += (j & 1) ? -p : p;
    }
    float4 zv;
    zv.x = z0; zv.y = z1; zv.z = z2; zv.w = z3;
    reinterpret_cast<float4*>(z)[b] = zv;
}

// ---------------------------------------------------------------------------
// Kernel 3: out[b][j] = sum_q z[b][q] * post_w[j][q] + post_b[j]
// One block per row; thread t produces columns 4t..4t+3 via float4 store.
// ---------------------------------------------------------------------------
__global__ __launch_bounds__(256) void post_kernel(
    const float* __restrict__ z, const float* __restrict__ pw,
    const float* __restrict__ pb, float* __restrict__ out)
{
    int row = blockIdx.x;
    int t = threadIdx.x;

    float4 zv = reinterpret_cast<const float4*>(z)[row];
    const float4* pwv = reinterpret_cast<const float4*>(pw);  // pwv[j] = post_w row j

    float4 w0 = pwv[4 * t + 0];
    float4 w1 = pwv[4 * t + 1];
    float4 w2 = pwv[4 * t + 2];
    float4 w3 = pwv[4 * t + 3];
    float4 bv = reinterpret_cast<const float4*>(pb)[t];

    float4 acc;
    acc.x = fmaf(zv.x, w0.x, fmaf(zv.y, w0.y, fmaf(zv.z, w0.z, fmaf(zv.w, w0.w, bv.x))));
    acc.y = fmaf(zv.x, w1.x, fmaf(zv.y, w1.y, fmaf(zv.z, w1.z, fmaf(zv.w, w1.w, bv.y))));
    acc.z = fmaf(zv.x, w2.x, fmaf(zv.y, w2.y, fmaf(zv.z, w2.z, fmaf(zv.w, w2.w, bv.z))));
    acc.w = fmaf(zv.x, w3.x, fmaf(zv.y, w3.y, fmaf(zv.z, w3.z, fmaf(zv.w, w3.w, bv.w))));

    reinterpret_cast<float4*>(out + (size_t)row * D_OUT_K)[t] = acc;
}

// ---------------------------------------------------------------------------
extern "C" void kernel_launch(void* const* d_in, const int* in_sizes, int n_in,
                              void* d_out, int out_size, void* d_ws, size_t ws_size,
                              hipStream_t stream)
{
    const float* x      = (const float*)d_in[0];  // (B, 1024)
    const float* pre_w  = (const float*)d_in[1];  // (4, 1024)
    const float* pre_b  = (const float*)d_in[2];  // (4,)
    const float* qw     = (const float*)d_in[3];  // (1, 4, 3)
    const float* post_w = (const float*)d_in[4];  // (1024, 4)
    const float* post_b = (const float*)d_in[5];  // (1024,)
    float* out = (float*)d_out;                   // (B, 1024) fp32

    const int B = in_sizes[0] / D_IN_K;           // 65536

    // Workspace layout: h (B*4 f32) then z (B*4 f32) -> 2 MB total.
    float* h = (float*)d_ws;
    float* z = h + (size_t)B * 4;

    pre_kernel<<<(B + 3) / 4, 256, 0, stream>>>(x, pre_w, pre_b, h, B);
    circuit_kernel<<<(B + 255) / 256, 256, 0, stream>>>(h, qw, z, B);
    post_kernel<<<B, 256, 0, stream>>>(z, post_w, post_b, out);
}

// Round 2
// 471.949 us; speedup vs baseline: 1.0251x; 1.0251x over previous
//
#include <hip/hip_runtime.h>
#include <math.h>

// Problem constants (match reference): B=65536, D_IN=1024, D_OUT=1024, 4 qubits, 1 layer.
#define D_IN_K  1024
#define D_OUT_K 1024

static constexpr float PI_F = 3.14159265358979323846f;

__device__ __forceinline__ float dot4(float4 a, float4 b, float acc) {
    return fmaf(a.x, b.x, fmaf(a.y, b.y, fmaf(a.z, b.z, fmaf(a.w, b.w, acc))));
}

// ---------------------------------------------------------------------------
// Kernel 1: h[b][q] = tanh( dot(x[b,:], pre_w[q,:]) + pre_b[q] ) * pi
// 4 rows per wave, 16 rows per block. pre_w chunks loaded once per wave and
// reused across the 4 rows (4x less L1 weight traffic than 1 row/wave).
// ---------------------------------------------------------------------------
__global__ __launch_bounds__(256) void pre_kernel(
    const float* __restrict__ x, const float* __restrict__ pw,
    const float* __restrict__ pb, float* __restrict__ h, int B)
{
    const int wave = threadIdx.x >> 6;
    const int lane = threadIdx.x & 63;
    const int row0 = blockIdx.x * 16 + wave * 4;
    if (row0 >= B) return;

    const float4* w0 = reinterpret_cast<const float4*>(pw);
    const float4* w1 = reinterpret_cast<const float4*>(pw + D_IN_K);
    const float4* w2 = reinterpret_cast<const float4*>(pw + 2 * D_IN_K);
    const float4* w3 = reinterpret_cast<const float4*>(pw + 3 * D_IN_K);
    const float4* x0 = reinterpret_cast<const float4*>(x + (size_t)(row0 + 0) * D_IN_K);
    const float4* x1 = reinterpret_cast<const float4*>(x + (size_t)(row0 + 1) * D_IN_K);
    const float4* x2 = reinterpret_cast<const float4*>(x + (size_t)(row0 + 2) * D_IN_K);
    const float4* x3 = reinterpret_cast<const float4*>(x + (size_t)(row0 + 3) * D_IN_K);

    float acc[4][4];
#pragma unroll
    for (int r = 0; r < 4; ++r)
#pragma unroll
        for (int q = 0; q < 4; ++q) acc[r][q] = 0.f;

#pragma unroll
    for (int k = 0; k < 4; ++k) {
        const int idx = lane + (k << 6);          // float4 index 0..255
        float4 a = w0[idx], b = w1[idx], c = w2[idx], d = w3[idx];
        float4 xv;
        xv = x0[idx];
        acc[0][0] = dot4(xv, a, acc[0][0]); acc[0][1] = dot4(xv, b, acc[0][1]);
        acc[0][2] = dot4(xv, c, acc[0][2]); acc[0][3] = dot4(xv, d, acc[0][3]);
        xv = x1[idx];
        acc[1][0] = dot4(xv, a, acc[1][0]); acc[1][1] = dot4(xv, b, acc[1][1]);
        acc[1][2] = dot4(xv, c, acc[1][2]); acc[1][3] = dot4(xv, d, acc[1][3]);
        xv = x2[idx];
        acc[2][0] = dot4(xv, a, acc[2][0]); acc[2][1] = dot4(xv, b, acc[2][1]);
        acc[2][2] = dot4(xv, c, acc[2][2]); acc[2][3] = dot4(xv, d, acc[2][3]);
        xv = x3[idx];
        acc[3][0] = dot4(xv, a, acc[3][0]); acc[3][1] = dot4(xv, b, acc[3][1]);
        acc[3][2] = dot4(xv, c, acc[3][2]); acc[3][3] = dot4(xv, d, acc[3][3]);
    }

    // Butterfly reduce: every lane ends with the full sums.
#pragma unroll
    for (int off = 1; off < 64; off <<= 1) {
#pragma unroll
        for (int r = 0; r < 4; ++r)
#pragma unroll
            for (int q = 0; q < 4; ++q)
                acc[r][q] += __shfl_xor(acc[r][q], off, 64);
    }

    // Lane r*4+q finalizes (row0+r, qubit q): 16 parallel tanh, coalesced store.
    float v = acc[0][0];
#pragma unroll
    for (int r = 0; r < 4; ++r)
#pragma unroll
        for (int q = 0; q < 4; ++q)
            if (lane == r * 4 + q) v = acc[r][q];

    if (lane < 16) {
        float s = tanhf(v + pb[lane & 3]) * PI_F;
        h[(size_t)row0 * 4 + lane] = s;
    }
}

// ---------------------------------------------------------------------------
// Kernel 2: 4-qubit statevector simulation, one thread per row, all 16 complex
// amplitudes in registers (fully unrolled, compile-time masks).
// Index convention (matches reference reshape (b,2,2,2,2)): wire w -> bit (3-w).
// ---------------------------------------------------------------------------
template <int MASK>
__device__ __forceinline__ void apply1q(
    float* pr, float* pim,
    float u00r, float u00i, float u01r, float u01i,
    float u10r, float u10i, float u11r, float u11i)
{
#pragma unroll
    for (int j = 0; j < 16; ++j) {
        if (j & MASK) continue;
        const int k = j | MASK;
        float a0r = pr[j], a0i = pim[j], a1r = pr[k], a1i = pim[k];
        pr[j]  = u00r * a0r - u00i * a0i + u01r * a1r - u01i * a1i;
        pim[j] = u00r * a0i + u00i * a0r + u01r * a1i + u01i * a1r;
        pr[k]  = u10r * a0r - u10i * a0i + u11r * a1r - u11i * a1i;
        pim[k] = u10r * a0i + u10i * a0r + u11r * a1i + u11i * a1r;
    }
}

template <int CMASK, int TMASK>
__device__ __forceinline__ void cnot(float* pr, float* pim)
{
#pragma unroll
    for (int j = 0; j < 16; ++j) {
        if ((j & CMASK) && !(j & TMASK)) {
            const int k = j | TMASK;
            float t;
            t = pr[j];  pr[j]  = pr[k];  pr[k]  = t;
            t = pim[j]; pim[j] = pim[k]; pim[k] = t;
        }
    }
}

template <int MASK>
__device__ __forceinline__ void encode_qubit(float* pr, float* pim, float f)
{
    const float r = 0.70710678118654752440f;
    // H
    apply1q<MASK>(pr, pim, r, 0.f, r, 0.f, r, 0.f, -r, 0.f);
    // RY(arctan(f))
    float th = atanf(f) * 0.5f;
    float s, c;
    sincosf(th, &s, &c);
    apply1q<MASK>(pr, pim, c, 0.f, -s, 0.f, s, 0.f, c, 0.f);
    // RZ(arctan(f^2)) = diag(e^{-ia/2}, e^{+ia/2})
    float al = atanf(f * f) * 0.5f;
    float sa, ca;
    sincosf(al, &sa, &ca);
    apply1q<MASK>(pr, pim, ca, -sa, 0.f, 0.f, 0.f, 0.f, ca, sa);
}

template <int MASK>
__device__ __forceinline__ void rot_qubit(float* pr, float* pim,
                                          float phi, float th, float om)
{
    float st, ct, sp, cp, sm, cm;
    sincosf(0.5f * th, &st, &ct);
    sincosf(0.5f * (phi + om), &sp, &cp);
    sincosf(0.5f * (phi - om), &sm, &cm);
    apply1q<MASK>(pr, pim,
                  ct * cp, -ct * sp,
                  -st * cm, -st * sm,
                  st * cm, -st * sm,
                  ct * cp, ct * sp);
}

__global__ __launch_bounds__(256) void circuit_kernel(
    const float* __restrict__ h, const float* __restrict__ qw,
    float* __restrict__ z, int B)
{
    int b = blockIdx.x * 256 + threadIdx.x;
    if (b >= B) return;

    float4 hv = reinterpret_cast<const float4*>(h)[b];

    float pr[16], pim[16];
#pragma unroll
    for (int j = 0; j < 16; ++j) { pr[j] = 0.f; pim[j] = 0.f; }
    pr[0] = 1.f;

    encode_qubit<8>(pr, pim, hv.x);
    encode_qubit<4>(pr, pim, hv.y);
    encode_qubit<2>(pr, pim, hv.z);
    encode_qubit<1>(pr, pim, hv.w);

    cnot<8, 4>(pr, pim);
    cnot<4, 2>(pr, pim);
    cnot<2, 1>(pr, pim);
    cnot<1, 8>(pr, pim);

    rot_qubit<8>(pr, pim, qw[0], qw[1], qw[2]);
    rot_qubit<4>(pr, pim, qw[3], qw[4], qw[5]);
    rot_qubit<2>(pr, pim, qw[6], qw[7], qw[8]);
    rot_qubit<1>(pr, pim, qw[9], qw[10], qw[11]);

    float z0 = 0.f, z1 = 0.f, z2 = 0.f, z3 = 0.f;
#pragma unroll
    for (int j = 0; j < 16; ++j) {
        float p = pr[j] * pr[j] + pim[j] * pim[j];
        z0 += (j & 8) ? -p : p;
        z1 += (j & 4) ? -p : p;
        z2 += (j & 2) ? -p : p;
        z3 += (j & 1) ? -p : p;
    }
    float4 zv;
    zv.x = z0; zv.y = z1; zv.z = z2; zv.w = z3;
    reinterpret_cast<float4*>(z)[b] = zv;
}

// ---------------------------------------------------------------------------
// Kernel 3: out[b][j] = sum_q z[b][q] * post_w[j][q] + post_b[j]
// 16 rows per block. Thread t owns columns {t, t+256, t+512, t+768}:
//  - post_w loads are lane-consecutive float4 (coalesced), loaded ONCE per
//    16 rows instead of per row.
//  - z[row] is a wave-uniform broadcast load.
//  - stores are lane-contiguous dwords.
// ---------------------------------------------------------------------------
__global__ __launch_bounds__(256) void post_kernel(
    const float* __restrict__ z, const float* __restrict__ pw,
    const float* __restrict__ pb, float* __restrict__ out, int B)
{
    const int t = threadIdx.x;
    const int row0 = blockIdx.x * 16;
    if (row0 >= B) return;

    const float4* pwv = reinterpret_cast<const float4*>(pw);  // pwv[c] = post_w row c
    float4 w[4];
    float bias[4];
#pragma unroll
    for (int j = 0; j < 4; ++j) {
        w[j]    = pwv[t + 256 * j];
        bias[j] = pb[t + 256 * j];
    }

    const float4* zv = reinterpret_cast<const float4*>(z);
#pragma unroll
    for (int r = 0; r < 16; ++r) {
        float4 zr = zv[row0 + r];
        float* orow = out + (size_t)(row0 + r) * D_OUT_K;
#pragma unroll
        for (int j = 0; j < 4; ++j) {
            float o = fmaf(zr.x, w[j].x,
                      fmaf(zr.y, w[j].y,
                      fmaf(zr.z, w[j].z,
                      fmaf(zr.w, w[j].w, bias[j]))));
            orow[t + 256 * j] = o;
        }
    }
}

// ---------------------------------------------------------------------------
extern "C" void kernel_launch(void* const* d_in, const int* in_sizes, int n_in,
                              void* d_out, int out_size, void* d_ws, size_t ws_size,
                              hipStream_t stream)
{
    const float* x      = (const float*)d_in[0];  // (B, 1024)
    const float* pre_w  = (const float*)d_in[1];  // (4, 1024)
    const float* pre_b  = (const float*)d_in[2];  // (4,)
    const float* qw     = (const float*)d_in[3];  // (1, 4, 3)
    const float* post_w = (const float*)d_in[4];  // (1024, 4)
    const float* post_b = (const float*)d_in[5];  // (1024,)
    float* out = (float*)d_out;                   // (B, 1024) fp32

    const int B = in_sizes[0] / D_IN_K;           // 65536

    // Workspace layout: h (B*4 f32) then z (B*4 f32) -> 2 MB total.
    float* h = (float*)d_ws;
    float* z = h + (size_t)B * 4;

    pre_kernel<<<(B + 15) / 16, 256, 0, stream>>>(x, pre_w, pre_b, h, B);
    circuit_kernel<<<(B + 255) / 256, 256, 0, stream>>>(h, qw, z, B);
    post_kernel<<<(B + 15) / 16, 256, 0, stream>>>(z, post_w, post_b, out, B);
}